// Round 2
// baseline (167.339 us; speedup 1.0000x reference)
//
#include <hip/hip_runtime.h>
#include <math.h>
#include <stdint.h>

// [SQ, B, NP, HN] fp32, unscaled QK^T softmax attention — fully fused:
// per-phase in-kernel f32->f16 conversion + swizzled LDS staging (no prep
// kernel, no f16 scratch round-trip, no workspace).
#define SQ 2048
#define NBH 32           // B*NP heads
#define HN 64
#define BQ 128           // queries per block (4 q-waves x 32)
#define BK2 128          // keys per loop phase (2 tiles, one per wave-group)
#define NP2 (SQ/BK2)     // 16 phases
#define TOK 2048         // floats between consecutive tokens (B*NP*HN)

typedef _Float16 half2v __attribute__((ext_vector_type(2)));
typedef _Float16 half4v __attribute__((ext_vector_type(4)));
typedef _Float16 half8v __attribute__((ext_vector_type(8)));
typedef float f32x16 __attribute__((ext_vector_type(16)));

__device__ __forceinline__ float fexp2(float x) {
#if __has_builtin(__builtin_amdgcn_exp2f)
  return __builtin_amdgcn_exp2f(x);
#else
  return exp2f(x);
#endif
}

// cross-half (lane ^ 32) reduce via v_permlane32_swap: 1 VALU op instead of a
// ds_bpermute round-trip on the softmax critical path.
__device__ __forceinline__ float xmax32(float x) {
#if __has_builtin(__builtin_amdgcn_permlane32_swap)
  auto r = __builtin_amdgcn_permlane32_swap(__float_as_int(x), __float_as_int(x),
                                            false, false);
  return fmaxf(__int_as_float(r[0]), __int_as_float(r[1]));
#else
  return fmaxf(x, __shfl_xor(x, 32, 64));
#endif
}
__device__ __forceinline__ float xadd32(float x) {
#if __has_builtin(__builtin_amdgcn_permlane32_swap)
  auto r = __builtin_amdgcn_permlane32_swap(__float_as_int(x), __float_as_int(x),
                                            false, false);
  return __int_as_float(r[0]) + __int_as_float(r[1]);
#else
  return x + __shfl_xor(x, 32, 64);
#endif
}

// ---- fused flash attention, S^T = K.Q^T via mfma_32x32x16_f16.
// KEY-SPLIT: 8 waves/block (512 thr). Waves 0-3 own the phase's first 64-key
// tile, waves 4-7 the second; each keeps private (m,l,acc); LDS merge at end.
// STAGING (new): each phase, all 512 threads cooperatively load the next
// 128-key f32 K/V tiles (issued right after the barrier -> a full phase of
// latency cover), convert to f16 with the same round-to-nearest casts the old
// prep kernel used (bit-identical LDS contents), and ds_write into the
// swizzled layouts the verified compute loop reads:
//   K: kbf[key*64 + ((chunk ^ (key&7))*8)]      (16B chunks, bank-balanced)
//   V: vtf[tile*4096 + dim*64 + ((u^(dim&15))*4) + (kl&3)]  (4-key units)
// C layout: col = lane&31, row = (reg&3)+8*(reg>>2)+4*(lane>>5).
// PV uses permuted k-order pi(h2,j)=16ks+4h2+8*(j>>2)+(j&3) so P^T stays in regs.
// Q pre-scaled by log2(e) -> bare v_exp_f32.
__global__ __launch_bounds__(512, 2)
void fattn_fused(const float* __restrict__ Q, const float* __restrict__ K,
                 const float* __restrict__ V, float* __restrict__ O) {
  // flat 64 KB: K dbuf [2][128][64-swz] | V dbuf [2][2][64][64-swz]
  __shared__ __align__(16) _Float16 smem[4 * 8192];
  _Float16* kbf = smem;            // 2 bufs x 8192 halfs
  _Float16* vtf = smem + 16384;    // 2 bufs x 8192 halfs

  const int t = threadIdx.x;
  const int lane = t & 63;
  const int w = t >> 6;            // 0..7
  const int qw = w & 3;            // query-wave within block
  const int g = w >> 2;            // key-group: 0 -> tile0, 1 -> tile1
  const int h2 = lane >> 5;
  const int l31 = lane & 31;
  const int q0 = blockIdx.x * BQ + qw * 32;
  const int head = blockIdx.y;
  const int tb = g * 4096;         // group's tile base (halfs) within a buffer

  // ---- staging thread roles (block-wide, independent of compute roles) ----
  // K: thread owns key (t>>2) of the 128-key tile, float chunks c0, c0+1 (8 ea)
  const int sk_key = t >> 2;                    // 0..127
  const int sk_c0 = (t & 3) * 2;
  const int sk_sw0 = ((sk_c0    ) ^ (sk_key & 7)) * 8;
  const int sk_sw1 = ((sk_c0 + 1) ^ (sk_key & 7)) * 8;
  const float* ksrc = K + (size_t)sk_key * TOK + head * HN + sk_c0 * 8;
  // V: thread owns keys (kl, kl+1) of tile tl, dims db..db+7
  const int sv_tl = t >> 8;                     // 0..1
  const int sv_tloc = t & 255;
  const int sv_kl = (sv_tloc >> 3) * 2;         // 0..62 even
  const int sv_db = (sv_tloc & 7) * 8;          // 0..56
  const int sv_u = sv_kl >> 2;                  // 4-key unit 0..15
  const int sv_k3 = sv_kl & 3;                  // 0 or 2
  const float* vsrc = V + (size_t)(sv_tl * 64 + sv_kl) * TOK + head * HN + sv_db;

  // ---- Q B-fragments x log2(e), registers all kernel ----
  half8v qf[4];
  {
    const float* qp = Q + (size_t)(q0 + l31) * TOK + head * HN + 8 * h2;
    const float s = 1.44269504088896f;
    #pragma unroll
    for (int ks = 0; ks < 4; ++ks) {
      float4 a = *(const float4*)(qp + 16 * ks);
      float4 b = *(const float4*)(qp + 16 * ks + 4);
      half8v f;
      f[0] = (_Float16)(s*a.x); f[1] = (_Float16)(s*a.y); f[2] = (_Float16)(s*a.z); f[3] = (_Float16)(s*a.w);
      f[4] = (_Float16)(s*b.x); f[5] = (_Float16)(s*b.y); f[6] = (_Float16)(s*b.z); f[7] = (_Float16)(s*b.w);
      qf[ks] = f;
    }
  }

  f32x16 acc0, acc1;   // O^T partial frags: dims 0..31, 32..63 (this group's keys)
  #pragma unroll
  for (int r = 0; r < 16; ++r) { acc0[r] = 0.f; acc1[r] = 0.f; }
  float m_i = -INFINITY, l_i = 0.f;

  // staged f32 tile (32 regs, live from post-barrier load to mid-phase write)
  float4 kr0, kr1, kr2, kr3, vr0, vr1, vr2, vr3;

  auto stage_load = [&](int p) {
    const size_t off = (size_t)p * BK2 * TOK;
    const float* ks = ksrc + off;
    kr0 = *(const float4*)(ks);
    kr1 = *(const float4*)(ks + 4);
    kr2 = *(const float4*)(ks + 8);
    kr3 = *(const float4*)(ks + 12);
    const float* vs = vsrc + off;
    vr0 = *(const float4*)(vs);
    vr1 = *(const float4*)(vs + 4);
    vr2 = *(const float4*)(vs + TOK);
    vr3 = *(const float4*)(vs + TOK + 4);
  };
  auto stage_write = [&](int p) {
    const int buf = p & 1;
    {   // K: two 16B swizzled chunks (round-to-nearest casts, same as old prep)
      half8v h0, h1;
      h0[0]=(_Float16)kr0.x; h0[1]=(_Float16)kr0.y; h0[2]=(_Float16)kr0.z; h0[3]=(_Float16)kr0.w;
      h0[4]=(_Float16)kr1.x; h0[5]=(_Float16)kr1.y; h0[6]=(_Float16)kr1.z; h0[7]=(_Float16)kr1.w;
      h1[0]=(_Float16)kr2.x; h1[1]=(_Float16)kr2.y; h1[2]=(_Float16)kr2.z; h1[3]=(_Float16)kr2.w;
      h1[4]=(_Float16)kr3.x; h1[5]=(_Float16)kr3.y; h1[6]=(_Float16)kr3.z; h1[7]=(_Float16)kr3.w;
      _Float16* row = kbf + buf * 8192 + sk_key * 64;
      *(half8v*)&row[sk_sw0] = h0;
      *(half8v*)&row[sk_sw1] = h1;
    }
    {   // V: 8 half2v writes into the (u ^ dim&15) swizzled transpose layout
      const float av[8] = {vr0.x,vr0.y,vr0.z,vr0.w,vr1.x,vr1.y,vr1.z,vr1.w};
      const float bv[8] = {vr2.x,vr2.y,vr2.z,vr2.w,vr3.x,vr3.y,vr3.z,vr3.w};
      _Float16* vrow = vtf + buf * 8192 + sv_tl * 4096;
      #pragma unroll
      for (int j = 0; j < 8; ++j) {
        const int dim = sv_db + j;
        const int pos = sv_u ^ (dim & 15);
        half2v h; h[0] = (_Float16)av[j]; h[1] = (_Float16)bv[j];
        *(half2v*)&vrow[dim * 64 + pos * 4 + sv_k3] = h;
      }
    }
  };

  stage_load(0);
  stage_write(0);
  for (int p = 0; p < NP2; ++p) {
    __syncthreads();                 // staged writes visible; prior readers done
    if (p + 1 < NP2) stage_load(p + 1);   // loads get a full phase of cover
    const int cur = p & 1;
    const _Float16* kb = kbf + cur * 8192 + tb;
    const _Float16* vb = vtf + cur * 8192 + tb;

    // ---- S^T = K . Q^T for this group's 64-key tile (2 chains) ----
    f32x16 c0, c1;
    #pragma unroll
    for (int r = 0; r < 16; ++r) { c0[r] = 0.f; c1[r] = 0.f; }
    #pragma unroll
    for (int ks = 0; ks < 4; ++ks) {
      const int pos = ((h2 + 2 * ks) ^ (l31 & 7)) * 8;
      half8v a0v = *(const half8v*)&kb[l31 * 64 + pos];
      half8v a1v = *(const half8v*)&kb[(l31 + 32) * 64 + pos];
      c0 = __builtin_amdgcn_mfma_f32_32x32x16_f16(a0v, qf[ks], c0, 0, 0, 0);
      c1 = __builtin_amdgcn_mfma_f32_32x32x16_f16(a1v, qf[ks], c1, 0, 0, 0);
    }

    // ---- online softmax over this group's 64 keys (log2 domain) ----
    float mx0 = fmaxf(c0[0], c1[0]);
    float mx1 = fmaxf(c0[1], c1[1]);
    float mx2 = fmaxf(c0[2], c1[2]);
    float mx3 = fmaxf(c0[3], c1[3]);
    #pragma unroll
    for (int r = 4; r < 16; r += 4) {
      mx0 = fmaxf(mx0, fmaxf(c0[r],     c1[r]));
      mx1 = fmaxf(mx1, fmaxf(c0[r + 1], c1[r + 1]));
      mx2 = fmaxf(mx2, fmaxf(c0[r + 2], c1[r + 2]));
      mx3 = fmaxf(mx3, fmaxf(c0[r + 3], c1[r + 3]));
    }
    float mx = fmaxf(fmaxf(mx0, mx1), fmaxf(mx2, mx3));
    mx = xmax32(mx);
    const float mnew = fmaxf(m_i, mx);
    const float alpha = fexp2(m_i - mnew);   // 0 on first phase
    float rs0 = 0.f, rs1 = 0.f;
    #pragma unroll
    for (int r = 0; r < 16; ++r) {
      float p0 = fexp2(c0[r] - mnew);
      float p1 = fexp2(c1[r] - mnew);
      c0[r] = p0; c1[r] = p1;
      rs0 += p0; rs1 += p1;
    }
    float rsum = xadd32(rs0 + rs1);
    l_i = l_i * alpha + rsum;
    m_i = mnew;
    #pragma unroll
    for (int r = 0; r < 16; ++r) { acc0[r] *= alpha; acc1[r] *= alpha; }

    // staged f32 -> f16 into buffer (p+1)&1 (disjoint from cur's readers);
    // placed here so the global loads had QK+softmax to land, and the
    // ds_writes have until next barrier to drain.
    if (p + 1 < NP2) stage_write(p + 1);

    // ---- PV for this tile: O^T += V^T . P^T, permuted k-order ----
    #pragma unroll
    for (int ks = 0; ks < 4; ++ks) {
      const int rb = 8 * (ks & 1);
      const f32x16& s = (ks < 2) ? c0 : c1;
      union { half8v v8; half2v v2[4]; } pu;
      #pragma unroll
      for (int tt = 0; tt < 4; ++tt) {
        auto pk = __builtin_amdgcn_cvt_pkrtz(s[rb + 2 * tt], s[rb + 2 * tt + 1]);
        pu.v2[tt] = *(half2v*)&pk;
      }
      #pragma unroll
      for (int mbd = 0; mbd < 2; ++mbd) {
        const int dim = l31 + 32 * mbd;
        const int sw = dim & 15;
        union { half8v v8; half4v v4[2]; } au;
        au.v4[0] = *(const half4v*)&vb[dim * 64 + ((4 * ks + h2)     ^ sw) * 4];
        au.v4[1] = *(const half4v*)&vb[dim * 64 + ((4 * ks + 2 + h2) ^ sw) * 4];
        if (mbd == 0)
          acc0 = __builtin_amdgcn_mfma_f32_32x32x16_f16(au.v8, pu.v8, acc0, 0, 0, 0);
        else
          acc1 = __builtin_amdgcn_mfma_f32_32x32x16_f16(au.v8, pu.v8, acc1, 0, 0, 0);
      }
    }
  }

  // ---- merge the two key-groups' partials via LDS, then write O ----
  __syncthreads();                       // all LDS reads of main loop done
  float* fb = (float*)smem;              // 16384 floats available
  const int slot = qw * 64 + lane;       // 0..255
  if (g == 1) {
    #pragma unroll
    for (int r = 0; r < 16; ++r) {
      fb[slot * 32 + r]      = acc0[r];
      fb[slot * 32 + 16 + r] = acc1[r];
    }
    fb[8192 + slot] = m_i;
    fb[8448 + slot] = l_i;
  }
  __syncthreads();
  if (g == 0) {
    const float m2 = fb[8192 + slot];
    const float l2 = fb[8448 + slot];
    const float ms = fmaxf(m_i, m2);
    const float a0 = fexp2(m_i - ms);
    const float a1 = fexp2(m2 - ms);
    const float invl = 1.f / (l_i * a0 + l2 * a1);
    float* orow = O + (size_t)(q0 + l31) * TOK + head * HN;
    #pragma unroll
    for (int r = 0; r < 16; ++r) {
      const int d = (r & 3) + 8 * (r >> 2) + 4 * h2;
      orow[d]      = (acc0[r] * a0 + fb[slot * 32 + r]      * a1) * invl;
      orow[d + 32] = (acc1[r] * a0 + fb[slot * 32 + 16 + r] * a1) * invl;
    }
  }
}

extern "C" void kernel_launch(void* const* d_in, const int* in_sizes, int n_in,
                              void* d_out, int out_size, void* d_ws, size_t ws_size,
                              hipStream_t stream) {
  const float* Q = (const float*)d_in[0];
  const float* K = (const float*)d_in[1];
  const float* V = (const float*)d_in[2];
  float* O = (float*)d_out;
  (void)d_ws; (void)ws_size;
  fattn_fused<<<dim3(SQ / BQ, NBH), 512, 0, stream>>>(Q, K, V, O);
}

// Round 3
// 143.645 us; speedup vs baseline: 1.1649x; 1.1649x over previous
//
#include <hip/hip_runtime.h>
#include <math.h>
#include <stdint.h>

// [SQ, B, NP, HN] fp32, unscaled QK^T softmax attention.
#define SQ 2048
#define NBH 32           // B*NP heads
#define HN 64
#define BQ 256           // queries per block (4 q-waves x 64)
#define BK2 128          // keys per loop phase (2 tiles, one per wave-group)
#define NP2 (SQ/BK2)     // 16 phases
#define TOK 2048         // floats between consecutive tokens (B*NP*HN)
#define HSTRIDE (SQ*HN)  // halfs per head in the f16 scratch layouts

typedef _Float16 half2v __attribute__((ext_vector_type(2)));
typedef _Float16 half4v __attribute__((ext_vector_type(4)));
typedef _Float16 half8v __attribute__((ext_vector_type(8)));
typedef float f32x16 __attribute__((ext_vector_type(16)));

__device__ __forceinline__ void async16(const void* g, void* l) {
  __builtin_amdgcn_global_load_lds(
      (const __attribute__((address_space(1))) void*)g,
      (__attribute__((address_space(3))) void*)l, 16, 0, 0);
}

__device__ __forceinline__ float fexp2(float x) {
#if __has_builtin(__builtin_amdgcn_exp2f)
  return __builtin_amdgcn_exp2f(x);
#else
  return exp2f(x);
#endif
}

// cross-half (lane ^ 32) reduce via v_permlane32_swap.
__device__ __forceinline__ float xmax32(float x) {
#if __has_builtin(__builtin_amdgcn_permlane32_swap)
  auto r = __builtin_amdgcn_permlane32_swap(__float_as_int(x), __float_as_int(x),
                                            false, false);
  return fmaxf(__int_as_float(r[0]), __int_as_float(r[1]));
#else
  return fmaxf(x, __shfl_xor(x, 32, 64));
#endif
}
__device__ __forceinline__ float xadd32(float x) {
#if __has_builtin(__builtin_amdgcn_permlane32_swap)
  auto r = __builtin_amdgcn_permlane32_swap(__float_as_int(x), __float_as_int(x),
                                            false, false);
  return __int_as_float(r[0]) + __int_as_float(r[1]);
#else
  return x + __shfl_xor(x, 32, 64);
#endif
}

// ---- prep (one launch): K -> Kh f16 [head][key][dim] (16B chunks xor-swizzled
// by key&7 within the 128B row); V -> Vt f16 [head][dim][key] (4-key units
// xor-swizzled by dim&15 within each 64-key tile).  (unchanged, verified)
__global__ __launch_bounds__(256) void prep_kv(const float* __restrict__ K,
                                               const float* __restrict__ V,
                                               _Float16* __restrict__ Kh,
                                               _Float16* __restrict__ Vt) {
  __shared__ _Float16 vs[HN * 64];
  const int t = threadIdx.x;
  const int head = blockIdx.y;
  // K part
  {
    const int key = blockIdx.x * 64 + (t >> 2);
    const int c0 = (t & 3) * 2;
    const float* src = K + (size_t)key * TOK + head * HN + c0 * 8;
    float4 a = *(const float4*)src;
    float4 b = *(const float4*)(src + 4);
    float4 c = *(const float4*)(src + 8);
    float4 d = *(const float4*)(src + 12);
    half8v h0, h1;
    h0[0]=(_Float16)a.x; h0[1]=(_Float16)a.y; h0[2]=(_Float16)a.z; h0[3]=(_Float16)a.w;
    h0[4]=(_Float16)b.x; h0[5]=(_Float16)b.y; h0[6]=(_Float16)b.z; h0[7]=(_Float16)b.w;
    h1[0]=(_Float16)c.x; h1[1]=(_Float16)c.y; h1[2]=(_Float16)c.z; h1[3]=(_Float16)c.w;
    h1[4]=(_Float16)d.x; h1[5]=(_Float16)d.y; h1[6]=(_Float16)d.z; h1[7]=(_Float16)d.w;
    _Float16* row = Kh + (size_t)head * HSTRIDE + (size_t)key * 64;
    *(half8v*)&row[((c0    ) ^ (key & 7)) * 8] = h0;
    *(half8v*)&row[((c0 + 1) ^ (key & 7)) * 8] = h1;
  }
  // V part
  {
    const int kt = blockIdx.x * 64;
    const int kl = (t >> 3) * 2;
    const int db = (t & 7) * 8;
    const float* src = V + (size_t)(kt + kl) * TOK + head * HN + db;
    float4 a0 = *(const float4*)src;
    float4 a1 = *(const float4*)(src + 4);
    float4 b0 = *(const float4*)(src + TOK);
    float4 b1 = *(const float4*)(src + TOK + 4);
    const float av[8] = {a0.x,a0.y,a0.z,a0.w,a1.x,a1.y,a1.z,a1.w};
    const float bv[8] = {b0.x,b0.y,b0.z,b0.w,b1.x,b1.y,b1.z,b1.w};
    const int u = kl >> 2;
    #pragma unroll
    for (int j = 0; j < 8; ++j) {
      const int dim = db + j;
      const int pos = u ^ (dim & 15);
      half2v h; h[0] = (_Float16)av[j]; h[1] = (_Float16)bv[j];
      *(half2v*)&vs[dim * 64 + pos * 4 + (kl & 3)] = h;
    }
    __syncthreads();
    const int dim = t >> 2;
    const int q = (t & 3) ^ (dim & 3);
    const _Float16* srow = &vs[dim * 64 + q * 16];
    _Float16* drow = Vt + (size_t)head * HSTRIDE + (size_t)dim * SQ + kt + q * 16;
    *(half8v*)&drow[0] = *(const half8v*)&srow[0];
    *(half8v*)&drow[8] = *(const half8v*)&srow[8];
  }
}

// ---- main: flash attention, S^T = K.Q^T via mfma_32x32x16_f16.
// KEY-SPLIT 8 waves (waves 0-3 tile0, 4-7 tile1 of each 128-key phase) AND
// 64 QUERIES PER WAVE (two 32-query B-fragment sets A/B). The same K/V LDS
// reads now feed 2x the MFMAs -> LDS bytes per query halved (the measured
// per-CU bottleneck). BQ=256, grid 8x32=256 blocks (1/CU, 2 waves/SIMD).
// C layout: col = lane&31 (query of the set), row = (reg&3)+8*(reg>>2)+4*(lane>>5).
// PV uses permuted k-order pi(h2,j)=16ks+4h2+8*(j>>2)+(j&3) so P^T stays in regs.
// Q pre-scaled by log2(e) -> bare v_exp_f32.
__global__ __launch_bounds__(512, 2)
void fattn_mfma(const float* __restrict__ Q, const _Float16* __restrict__ Kh,
                const _Float16* __restrict__ Vt, float* __restrict__ O) {
  // flat 64 KB: K dbuf [2][128][64-swz] | V dbuf [2][2][64][64-swz]
  __shared__ __align__(16) _Float16 smem[4 * 8192];
  _Float16* kbf = smem;            // 2 bufs x 8192 halfs
  _Float16* vtf = smem + 16384;    // 2 bufs x 8192 halfs

  const int t = threadIdx.x;
  const int lane = t & 63;
  const int w = t >> 6;            // 0..7
  const int qw = w & 3;            // query-wave within block (64 q each)
  const int g = w >> 2;            // key-group: 0 -> tile0, 1 -> tile1
  const int h2 = lane >> 5;
  const int l31 = lane & 31;
  const int q0 = blockIdx.x * BQ + qw * 64;
  const int head = blockIdx.y;
  const _Float16* Kp = Kh + (size_t)head * HSTRIDE;
  const _Float16* Vp = Vt + (size_t)head * HSTRIDE;
  const int tb = g * 4096;         // group's tile base (halfs) within a buffer

  // ---- Q B-fragments x log2(e): set A = queries q0+l31, set B = q0+32+l31 ----
  half8v qfA[4], qfB[4];
  {
    const float s = 1.44269504088896f;
    const float* qpA = Q + (size_t)(q0 + l31) * TOK + head * HN + 8 * h2;
    const float* qpB = qpA + (size_t)32 * TOK;
    #pragma unroll
    for (int ks = 0; ks < 4; ++ks) {
      float4 a = *(const float4*)(qpA + 16 * ks);
      float4 b = *(const float4*)(qpA + 16 * ks + 4);
      half8v f;
      f[0] = (_Float16)(s*a.x); f[1] = (_Float16)(s*a.y); f[2] = (_Float16)(s*a.z); f[3] = (_Float16)(s*a.w);
      f[4] = (_Float16)(s*b.x); f[5] = (_Float16)(s*b.y); f[6] = (_Float16)(s*b.z); f[7] = (_Float16)(s*b.w);
      qfA[ks] = f;
      a = *(const float4*)(qpB + 16 * ks);
      b = *(const float4*)(qpB + 16 * ks + 4);
      f[0] = (_Float16)(s*a.x); f[1] = (_Float16)(s*a.y); f[2] = (_Float16)(s*a.z); f[3] = (_Float16)(s*a.w);
      f[4] = (_Float16)(s*b.x); f[5] = (_Float16)(s*b.y); f[6] = (_Float16)(s*b.z); f[7] = (_Float16)(s*b.w);
      qfB[ks] = f;
    }
  }

  f32x16 accA0, accA1, accB0, accB1;  // O^T partials per set: dims 0..31, 32..63
  #pragma unroll
  for (int r = 0; r < 16; ++r) { accA0[r]=0.f; accA1[r]=0.f; accB0[r]=0.f; accB1[r]=0.f; }
  float mA = -INFINITY, lA = 0.f, mB = -INFINITY, lB = 0.f;

  // async stage of phase p into buffer p&1; split across all 8 waves. (verified)
  auto stage = [&](int p) {
    const int buf = p & 1;
    const size_t kt = (size_t)p * BK2;
    #pragma unroll
    for (int i = 0; i < 2; ++i) {                 // K: 16 KB
      const int off = w * 512 + i * 4096;
      async16(Kp + kt * 64 + off + lane * 8, kbf + buf * 8192 + off);
    }
    #pragma unroll
    for (int tl = 0; tl < 2; ++tl) {              // V: 16 KB
      const int off = w * 512;
      const int eo = off + lane * 8;
      const int dim = eo >> 6, inner = eo & 63;
      async16(Vp + (size_t)dim * SQ + kt + tl * 64 + inner,
              vtf + buf * 8192 + tl * 4096 + off);
    }
  };

  stage(0);
  for (int p = 0; p < NP2; ++p) {
    __syncthreads();                 // drains vmcnt: buf p&1 ready; prior readers done
    if (p + 1 < NP2) stage(p + 1);   // overlaps all compute below
    const int cur = p & 1;
    const _Float16* kb = kbf + cur * 8192 + tb;
    const _Float16* vb = vtf + cur * 8192 + tb;

    // ---- S^T = K . Q^T for this group's 64-key tile, both query sets ----
    f32x16 cA0, cA1, cB0, cB1;
    #pragma unroll
    for (int r = 0; r < 16; ++r) { cA0[r]=0.f; cA1[r]=0.f; cB0[r]=0.f; cB1[r]=0.f; }
    #pragma unroll
    for (int ks = 0; ks < 4; ++ks) {
      const int pos = ((h2 + 2 * ks) ^ (l31 & 7)) * 8;
      half8v a0v = *(const half8v*)&kb[l31 * 64 + pos];
      half8v a1v = *(const half8v*)&kb[(l31 + 32) * 64 + pos];
      cA0 = __builtin_amdgcn_mfma_f32_32x32x16_f16(a0v, qfA[ks], cA0, 0, 0, 0);
      cB0 = __builtin_amdgcn_mfma_f32_32x32x16_f16(a0v, qfB[ks], cB0, 0, 0, 0);
      cA1 = __builtin_amdgcn_mfma_f32_32x32x16_f16(a1v, qfA[ks], cA1, 0, 0, 0);
      cB1 = __builtin_amdgcn_mfma_f32_32x32x16_f16(a1v, qfB[ks], cB1, 0, 0, 0);
    }

    // ---- online softmax (log2 domain), set A ----
    {
      float mx0 = fmaxf(cA0[0], cA1[0]);
      float mx1 = fmaxf(cA0[1], cA1[1]);
      float mx2 = fmaxf(cA0[2], cA1[2]);
      float mx3 = fmaxf(cA0[3], cA1[3]);
      #pragma unroll
      for (int r = 4; r < 16; r += 4) {
        mx0 = fmaxf(mx0, fmaxf(cA0[r],     cA1[r]));
        mx1 = fmaxf(mx1, fmaxf(cA0[r + 1], cA1[r + 1]));
        mx2 = fmaxf(mx2, fmaxf(cA0[r + 2], cA1[r + 2]));
        mx3 = fmaxf(mx3, fmaxf(cA0[r + 3], cA1[r + 3]));
      }
      float mx = xmax32(fmaxf(fmaxf(mx0, mx1), fmaxf(mx2, mx3)));
      const float mnew = fmaxf(mA, mx);
      const float alpha = fexp2(mA - mnew);
      float rs0 = 0.f, rs1 = 0.f;
      #pragma unroll
      for (int r = 0; r < 16; ++r) {
        float p0 = fexp2(cA0[r] - mnew);
        float p1 = fexp2(cA1[r] - mnew);
        cA0[r] = p0; cA1[r] = p1;
        rs0 += p0; rs1 += p1;
      }
      lA = lA * alpha + xadd32(rs0 + rs1);
      mA = mnew;
      #pragma unroll
      for (int r = 0; r < 16; ++r) { accA0[r] *= alpha; accA1[r] *= alpha; }
    }
    // ---- online softmax, set B ----
    {
      float mx0 = fmaxf(cB0[0], cB1[0]);
      float mx1 = fmaxf(cB0[1], cB1[1]);
      float mx2 = fmaxf(cB0[2], cB1[2]);
      float mx3 = fmaxf(cB0[3], cB1[3]);
      #pragma unroll
      for (int r = 4; r < 16; r += 4) {
        mx0 = fmaxf(mx0, fmaxf(cB0[r],     cB1[r]));
        mx1 = fmaxf(mx1, fmaxf(cB0[r + 1], cB1[r + 1]));
        mx2 = fmaxf(mx2, fmaxf(cB0[r + 2], cB1[r + 2]));
        mx3 = fmaxf(mx3, fmaxf(cB0[r + 3], cB1[r + 3]));
      }
      float mx = xmax32(fmaxf(fmaxf(mx0, mx1), fmaxf(mx2, mx3)));
      const float mnew = fmaxf(mB, mx);
      const float alpha = fexp2(mB - mnew);
      float rs0 = 0.f, rs1 = 0.f;
      #pragma unroll
      for (int r = 0; r < 16; ++r) {
        float p0 = fexp2(cB0[r] - mnew);
        float p1 = fexp2(cB1[r] - mnew);
        cB0[r] = p0; cB1[r] = p1;
        rs0 += p0; rs1 += p1;
      }
      lB = lB * alpha + xadd32(rs0 + rs1);
      mB = mnew;
      #pragma unroll
      for (int r = 0; r < 16; ++r) { accB0[r] *= alpha; accB1[r] *= alpha; }
    }

    // ---- PV: O^T += V^T . P^T, permuted k-order; V frags shared across sets ----
    #pragma unroll
    for (int ks = 0; ks < 4; ++ks) {
      const int rb = 8 * (ks & 1);
      const f32x16& sA = (ks < 2) ? cA0 : cA1;
      const f32x16& sB = (ks < 2) ? cB0 : cB1;
      union { half8v v8; half2v v2[4]; } puA, puB;
      #pragma unroll
      for (int tt = 0; tt < 4; ++tt) {
        auto pkA = __builtin_amdgcn_cvt_pkrtz(sA[rb + 2 * tt], sA[rb + 2 * tt + 1]);
        puA.v2[tt] = *(half2v*)&pkA;
        auto pkB = __builtin_amdgcn_cvt_pkrtz(sB[rb + 2 * tt], sB[rb + 2 * tt + 1]);
        puB.v2[tt] = *(half2v*)&pkB;
      }
      #pragma unroll
      for (int mbd = 0; mbd < 2; ++mbd) {
        const int dim = l31 + 32 * mbd;
        const int sw = dim & 15;
        union { half8v v8; half4v v4[2]; } au;
        au.v4[0] = *(const half4v*)&vb[dim * 64 + ((4 * ks + h2)     ^ sw) * 4];
        au.v4[1] = *(const half4v*)&vb[dim * 64 + ((4 * ks + 2 + h2) ^ sw) * 4];
        if (mbd == 0) {
          accA0 = __builtin_amdgcn_mfma_f32_32x32x16_f16(au.v8, puA.v8, accA0, 0, 0, 0);
          accB0 = __builtin_amdgcn_mfma_f32_32x32x16_f16(au.v8, puB.v8, accB0, 0, 0, 0);
        } else {
          accA1 = __builtin_amdgcn_mfma_f32_32x32x16_f16(au.v8, puA.v8, accA1, 0, 0, 0);
          accB1 = __builtin_amdgcn_mfma_f32_32x32x16_f16(au.v8, puB.v8, accB1, 0, 0, 0);
        }
      }
    }
  }

  // ---- merge the two key-groups' partials via LDS (per query set), write O ----
  float* fb = (float*)smem;              // 16384 floats
  const int slot = qw * 64 + lane;       // 0..255
  // set A
  __syncthreads();                       // all LDS reads of main loop done
  if (g == 1) {
    #pragma unroll
    for (int r = 0; r < 16; ++r) {
      fb[slot * 32 + r]      = accA0[r];
      fb[slot * 32 + 16 + r] = accA1[r];
    }
    fb[8192 + slot] = mA;
    fb[8448 + slot] = lA;
  }
  __syncthreads();
  if (g == 0) {
    const float m2 = fb[8192 + slot];
    const float l2 = fb[8448 + slot];
    const float ms = fmaxf(mA, m2);
    const float a0 = fexp2(mA - ms);
    const float a1 = fexp2(m2 - ms);
    const float invl = 1.f / (lA * a0 + l2 * a1);
    float* orow = O + (size_t)(q0 + l31) * TOK + head * HN;
    #pragma unroll
    for (int r = 0; r < 16; ++r) {
      const int d = (r & 3) + 8 * (r >> 2) + 4 * h2;
      orow[d]      = (accA0[r] * a0 + fb[slot * 32 + r]      * a1) * invl;
      orow[d + 32] = (accA1[r] * a0 + fb[slot * 32 + 16 + r] * a1) * invl;
    }
  }
  // set B
  __syncthreads();
  if (g == 1) {
    #pragma unroll
    for (int r = 0; r < 16; ++r) {
      fb[slot * 32 + r]      = accB0[r];
      fb[slot * 32 + 16 + r] = accB1[r];
    }
    fb[8192 + slot] = mB;
    fb[8448 + slot] = lB;
  }
  __syncthreads();
  if (g == 0) {
    const float m2 = fb[8192 + slot];
    const float l2 = fb[8448 + slot];
    const float ms = fmaxf(mB, m2);
    const float a0 = fexp2(mB - ms);
    const float a1 = fexp2(m2 - ms);
    const float invl = 1.f / (lB * a0 + l2 * a1);
    float* orow = O + (size_t)(q0 + 32 + l31) * TOK + head * HN;
    #pragma unroll
    for (int r = 0; r < 16; ++r) {
      const int d = (r & 3) + 8 * (r >> 2) + 4 * h2;
      orow[d]      = (accB0[r] * a0 + fb[slot * 32 + r]      * a1) * invl;
      orow[d + 32] = (accB1[r] * a0 + fb[slot * 32 + 16 + r] * a1) * invl;
    }
  }
}

extern "C" void kernel_launch(void* const* d_in, const int* in_sizes, int n_in,
                              void* d_out, int out_size, void* d_ws, size_t ws_size,
                              hipStream_t stream) {
  const float* Q = (const float*)d_in[0];
  const float* K = (const float*)d_in[1];
  const float* V = (const float*)d_in[2];
  float* O = (float*)d_out;
  _Float16* Kh = (_Float16*)d_ws;                       // 8 MB
  _Float16* Vh = Kh + (size_t)NBH * HSTRIDE;            // 8 MB
  prep_kv<<<dim3(SQ / 64, NBH), 256, 0, stream>>>(K, V, Kh, Vh);
  fattn_mfma<<<dim3(SQ / BQ, NBH), 512, 0, stream>>>(Q, Kh, Vh, O);
}